// Round 7
// baseline (230.369 us; speedup 1.0000x reference)
//
#include <hip/hip_runtime.h>
#include <hip/hip_bf16.h>

// LocalAttn: B=8 S=1024 E=512 H=16 D=32, rel-pos bias, NO causal mask.
// f32 inputs / f32 output. Internals bf16 for MFMA.
// R7: (a) convert fused into proj (f32 loads + in-reg cvt; only tiny Er
// convert remains) -- probe: does the constant ~112us non-attn residual
// track proj structure or is it fixed overhead? (b) attn: K/Er register
// ping-pong prefetch (one 64-chunk ahead), row-sums via ones-B MFMA
// (kills 32 VALU/iter + epilogue shuffles), V single-buffered.

typedef short bf16x8 __attribute__((ext_vector_type(8)));   // 8 bf16 (4 VGPRs)
typedef float f32x4 __attribute__((ext_vector_type(4)));
typedef unsigned short u16x4 __attribute__((ext_vector_type(4)));
typedef unsigned int u32x4 __attribute__((ext_vector_type(4)));

#if __has_builtin(__builtin_amdgcn_exp2f)
#define EXP2F(x) __builtin_amdgcn_exp2f(x)
#else
#define EXP2F(x) exp2f(x)
#endif

constexpr int Bb = 8, Ss = 1024, Ee = 512, Hh = 16, Dd = 32;
// log2(e)/sqrt(32): folds the 1/sqrt(D) softmax scale and exp->exp2 into Q.
#define QSCALE 0.25503486f

__device__ __forceinline__ bf16x8 ldg_frag(const __hip_bfloat16* p) {
    return *reinterpret_cast<const bf16x8*>(p);
}

__device__ __forceinline__ unsigned short bf16_bits(float v) {
    return __builtin_bit_cast(unsigned short, __float2bfloat16(v));
}

__device__ __forceinline__ unsigned pack_bf16(float lo, float hi) {
    return (unsigned)bf16_bits(lo) | ((unsigned)bf16_bits(hi) << 16);
}

__device__ __forceinline__ float bperm_f(int addr, float v) {
    return __builtin_bit_cast(float,
        __builtin_amdgcn_ds_bpermute(addr, __builtin_bit_cast(int, v)));
}

// load 8 consecutive f32, convert to a bf16x8 MFMA fragment
__device__ __forceinline__ bf16x8 ldg_f32_frag(const float* p) {
    const float4 a = *reinterpret_cast<const float4*>(p);
    const float4 b = *reinterpret_cast<const float4*>(p + 4);
    u32x4 pk;
    pk[0] = pack_bf16(a.x, a.y);
    pk[1] = pack_bf16(a.z, a.w);
    pk[2] = pack_bf16(b.x, b.y);
    pk[3] = pack_bf16(b.z, b.w);
    return __builtin_bit_cast(bf16x8, pk);
}

// ---------------- Er f32 -> bf16 (rows 0..2046; row 2047 zero pad) --------
__global__ __launch_bounds__(256) void er_convert_kernel(
    const float* __restrict__ er, __hip_bfloat16* __restrict__ erb)
{
    const int GE = 16376;                    // 2047*32/4 float4 groups
    int g = blockIdx.x * 256 + threadIdx.x;  // grid 64 -> 16384 threads
    u16x4 pk = {0, 0, 0, 0};
    if (g < GE) {
        const float4 v = *reinterpret_cast<const float4*>(er + (size_t)g * 4);
        pk[0] = bf16_bits(v.x);
        pk[1] = bf16_bits(v.y);
        pk[2] = bf16_bits(v.z);
        pk[3] = bf16_bits(v.w);
    }
    *reinterpret_cast<u16x4*>(erb + (size_t)g * 4) = pk;
}

// ---------------- projection: Q/K/V = x @ W^T (f32 in, fused convert) -----
// grid (6,128): WG = 64 rows x 256 cols of [Q|K|V]; wave = 64x64.
// V epilogue writes INTERLEAVED Vti: u32[d][512], slot (s>>5)*16+(s&15)
// packs the bf16 pair (V[s], V[s+16]) of each 32-block.
__global__ __launch_bounds__(256) void proj_kernel(
    const float* __restrict__ x,    // [8192][512] f32
    const float* __restrict__ wq,   // [512][512] f32
    const float* __restrict__ wk,
    const float* __restrict__ wv,
    __hip_bfloat16* __restrict__ Qs,   // [B][H][S][D], scaled by QSCALE
    __hip_bfloat16* __restrict__ Kh,   // [B][H][S][D]
    unsigned* __restrict__ Vt32)       // [B][H][D][512 u32] interleaved
{
    const int tid  = threadIdx.x;
    const int wave = tid >> 6;
    const int lane = tid & 63;
    const int li   = lane & 15;
    const int quad = lane >> 4;

    const int m0    = blockIdx.y * 64;
    const int nbase = blockIdx.x * 256 + wave * 64;   // multiple of 64
    const int mat   = nbase >> 9;      // 0=Q 1=K 2=V (uniform per wave)
    const int nn0   = nbase & 511;
    const float* W  = (mat == 0) ? wq : (mat == 1) ? wk : wv;

    f32x4 acc[4][4];
    #pragma unroll
    for (int rf = 0; rf < 4; ++rf)
        #pragma unroll
        for (int t = 0; t < 4; ++t) acc[rf][t] = f32x4{0.f, 0.f, 0.f, 0.f};

    const float* xp = x + (size_t)(m0 + li) * Ee + quad * 8;
    const float* wp = W + (size_t)(nn0 + li) * Ee + quad * 8;

    for (int k0 = 0; k0 < Ee; k0 += 32) {
        bf16x8 a[4], bfr[4];
        #pragma unroll
        for (int rf = 0; rf < 4; ++rf) a[rf]  = ldg_f32_frag(xp + rf * 16 * Ee + k0);
        #pragma unroll
        for (int t = 0; t < 4; ++t)    bfr[t] = ldg_f32_frag(wp + t * 16 * Ee + k0);
        #pragma unroll
        for (int rf = 0; rf < 4; ++rf)
            #pragma unroll
            for (int t = 0; t < 4; ++t)
                acc[rf][t] = __builtin_amdgcn_mfma_f32_16x16x32_bf16(
                    a[rf], bfr[t], acc[rf][t], 0, 0, 0);
    }

    // epilogue. C layout: col = li, row = quad*4 + reg.
    const int bb = m0 >> 10;           // 64-row block never straddles b
    const int sb = m0 & 1023;
    if (mat == 2) {
        #pragma unroll
        for (int t = 0; t < 4; ++t) {
            int nn = nn0 + t * 16 + li;
            int h = nn >> 5, d = nn & 31;
            size_t base = ((size_t)(bb * Hh + h) * Dd + d) * 512
                        + (sb >> 5) * 16 + quad * 4;
            #pragma unroll
            for (int p = 0; p < 2; ++p) {      // rf pair (2p, 2p+1)
                u32x4 pk;
                #pragma unroll
                for (int r = 0; r < 4; ++r)
                    pk[r] = pack_bf16(acc[2*p][t][r], acc[2*p+1][t][r]);
                *reinterpret_cast<u32x4*>(Vt32 + base + (size_t)p * 16) = pk;
            }
        }
    } else {
        __hip_bfloat16* dst = (mat == 0) ? Qs : Kh;
        const float sc = (mat == 0) ? QSCALE : 1.0f;
        #pragma unroll
        for (int rf = 0; rf < 4; ++rf) {
            const int srow = sb + rf * 16 + quad * 4;
            #pragma unroll
            for (int t = 0; t < 4; ++t) {
                int nn = nn0 + t * 16 + li;
                int h = nn >> 5, d = nn & 31;
                #pragma unroll
                for (int r = 0; r < 4; ++r)
                    dst[((size_t)(bb * Hh + h) * Ss + (srow + r)) * Dd + d] =
                        __float2bfloat16(acc[rf][t][r] * sc);
            }
        }
    }
}

// ---------------- attention -----------------------------------------------
// grid 1024; (b,h) = blockIdx&127 (XCD-local), ib = blockIdx>>7.
// Wave owns TWO 16-row Q strips (32 rows). j advances 128/loop-iter in two
// 64-col half-iters; K+Er register ping-pong prefetched one half ahead.
// Row sums via ones-B MFMA (no VALU adds, no epilogue shuffles).
#define LOADKE(K, E, kp, ep) do {                                   \
    K[0] = ldg_frag(kp);                                            \
    K[1] = ldg_frag(kp + 16 * Dd);                                  \
    K[2] = ldg_frag(kp + 32 * Dd);                                  \
    K[3] = ldg_frag(kp + 48 * Dd);                                  \
    E[0] = ldg_frag(ep - 32 * Dd);                                  \
    E[1] = ldg_frag(ep - 16 * Dd);                                  \
    E[2] = ldg_frag(ep);                                            \
    E[3] = ldg_frag(ep + 16 * Dd);                                  \
    E[4] = ldg_frag(ep + 32 * Dd);                                  \
    E[5] = ldg_frag(ep + 48 * Dd);                                  \
} while (0)

#define ATTN_STEP(QF, K, E, EOFF, V, PB0, PB1, O0, O1, OL) do {     \
    f32x4 s0 = __builtin_amdgcn_mfma_f32_16x16x32_bf16(QF, K[0], zero, 0, 0, 0); \
    f32x4 s1 = __builtin_amdgcn_mfma_f32_16x16x32_bf16(QF, K[1], zero, 0, 0, 0); \
    f32x4 s2 = __builtin_amdgcn_mfma_f32_16x16x32_bf16(QF, K[2], zero, 0, 0, 0); \
    f32x4 s3 = __builtin_amdgcn_mfma_f32_16x16x32_bf16(QF, K[3], zero, 0, 0, 0); \
    f32x4 q0 = __builtin_amdgcn_mfma_f32_16x16x32_bf16(QF, E[(EOFF)+0], zero, 0, 0, 0); \
    f32x4 q1 = __builtin_amdgcn_mfma_f32_16x16x32_bf16(QF, E[(EOFF)+1], zero, 0, 0, 0); \
    f32x4 q2 = __builtin_amdgcn_mfma_f32_16x16x32_bf16(QF, E[(EOFF)+2], zero, 0, 0, 0); \
    f32x4 q3 = __builtin_amdgcn_mfma_f32_16x16x32_bf16(QF, E[(EOFF)+3], zero, 0, 0, 0); \
    f32x4 q4 = __builtin_amdgcn_mfma_f32_16x16x32_bf16(QF, E[(EOFF)+4], zero, 0, 0, 0); \
    float p0[4], p1[4], p2[4], p3[4];                               \
    _Pragma("unroll")                                               \
    for (int r = 0; r < 4; ++r) {                                   \
        float f0 = bperm_f(addr4[r], q0[r]);                        \
        float f1 = bperm_f(addr4[r], q1[r]);                        \
        float f2 = bperm_f(addr4[r], q2[r]);                        \
        float f3 = bperm_f(addr4[r], q3[r]);                        \
        float f4 = bperm_f(addr4[r], q4[r]);                        \
        p0[r] = EXP2F(s0[r] + (cond[r] ? f0 : f1));                 \
        p1[r] = EXP2F(s1[r] + (cond[r] ? f1 : f2));                 \
        p2[r] = EXP2F(s2[r] + (cond[r] ? f2 : f3));                 \
        p3[r] = EXP2F(s3[r] + (cond[r] ? f3 : f4));                 \
    }                                                               \
    _Pragma("unroll")                                               \
    for (int r = 0; r < 4; ++r) {                                   \
        PB0[pbw + 20 * r] = pack_bf16(p0[r], p1[r]);                \
        PB1[pbw + 20 * r] = pack_bf16(p2[r], p3[r]);                \
    }                                                               \
    bf16x8 pf0 = *reinterpret_cast<const bf16x8*>(&PB0[pbr]);       \
    bf16x8 pf1 = *reinterpret_cast<const bf16x8*>(&PB1[pbr]);       \
    O0 = __builtin_amdgcn_mfma_f32_16x16x32_bf16(pf0, V[0], O0, 0, 0, 0); \
    O1 = __builtin_amdgcn_mfma_f32_16x16x32_bf16(pf0, V[1], O1, 0, 0, 0); \
    OL = __builtin_amdgcn_mfma_f32_16x16x32_bf16(pf0, onesb, OL, 0, 0, 0); \
    O0 = __builtin_amdgcn_mfma_f32_16x16x32_bf16(pf1, V[2], O0, 0, 0, 0); \
    O1 = __builtin_amdgcn_mfma_f32_16x16x32_bf16(pf1, V[3], O1, 0, 0, 0); \
    OL = __builtin_amdgcn_mfma_f32_16x16x32_bf16(pf1, onesb, OL, 0, 0, 0); \
} while (0)

__global__ __launch_bounds__(256) void attn_kernel(
    const __hip_bfloat16* __restrict__ Qs,
    const __hip_bfloat16* __restrict__ Kh,
    const __hip_bfloat16* __restrict__ Vt,   // bf16 view of Vti (same bytes)
    const __hip_bfloat16* __restrict__ Er,   // [2048][32] bf16, row 2047 = 0
    float* __restrict__ out)                 // [B][S][E] f32
{
    const int tid  = threadIdx.x;
    const int wave = tid >> 6;
    const int lane = tid & 63;
    const int li   = lane & 15;
    const int quad = lane >> 4;

    const int c  = blockIdx.x & 127;
    const int b  = c >> 4;
    const int h  = c & 15;
    const int ib = blockIdx.x >> 7;          // 0..7
    const int i0 = ib * 128 + wave * 32;     // strip A rows i0.., B rows i0+16..

    const __hip_bfloat16* Qp = Qs + (size_t)(b * Hh + h) * Ss * Dd;
    const __hip_bfloat16* Kp = Kh + (size_t)(b * Hh + h) * Ss * Dd;
    const __hip_bfloat16* Vp = Vt + (size_t)(b * Hh + h) * Dd * Ss;

    __shared__ unsigned pb_lds[4][4][16 * 20];   // 20480 B total
    unsigned* pbA0 = pb_lds[wave][0];
    unsigned* pbA1 = pb_lds[wave][1];
    unsigned* pbB0 = pb_lds[wave][2];
    unsigned* pbB1 = pb_lds[wave][3];

    const bf16x8 qfA = ldg_frag(Qp + (i0      + li) * Dd + quad * 8);
    const bf16x8 qfB = ldg_frag(Qp + (i0 + 16 + li) * Dd + quad * 8);

    // band element (row, bc=li-row+15): lane 16*quad + (bc&15), reg row&3.
    int addr4[4];
    bool cond[4];
    #pragma unroll
    for (int r = 0; r < 4; ++r) {
        const int row = quad * 4 + r;
        addr4[r] = (16 * quad + ((li - row + 15) & 15)) * 4;
        cond[r]  = (li <= row);            // bc < 16 -> lower band block
    }
    const int pbw = quad * 80 + li;        // pb write base (u32)
    const int pbr = li * 20 + quad * 4;    // pb read base (16B aligned)

    const bf16x8 onesb = {16256,16256,16256,16256,16256,16256,16256,16256};
    const f32x4 zero = f32x4{0,0,0,0};
    f32x4 oA0 = zero, oA1 = zero, oB0 = zero, oB1 = zero;
    f32x4 oLA = zero, oLB = zero;          // row sums (every col = rowsum)

    // rolling pointers. E base = band block E[2] (strip A's e1).
    const __hip_bfloat16* kpa  = Kp + li * Dd + quad * 8;            // j0=0
    const __hip_bfloat16* kpb  = kpa + 64 * Dd;                      // j0=64
    const __hip_bfloat16* epa  = Er + (size_t)(1024 - i0 + li) * Dd + quad * 8;
    const __hip_bfloat16* epb  = epa + 64 * Dd;
    const __hip_bfloat16* vpa0 = Vp + li * Ss + quad * 8;
    const __hip_bfloat16* vpa1 = Vp + (li + 16) * Ss + quad * 8;
    const __hip_bfloat16* vpb0 = vpa0 + 64;
    const __hip_bfloat16* vpb1 = vpa1 + 64;

    bf16x8 aK[4], aE[6], bK[4], bE[6];
    LOADKE(aK, aE, kpa, epa);
    LOADKE(bK, bE, kpb, epb);

    for (int jj = 0; jj < 8; ++jj) {
        {   // half-iter A: j0 = jj*128
            bf16x8 V[4];
            V[0] = ldg_frag(vpa0);      V[1] = ldg_frag(vpa1);
            V[2] = ldg_frag(vpa0 + 32); V[3] = ldg_frag(vpa1 + 32);
            vpa0 += 128; vpa1 += 128;
            ATTN_STEP(qfA, aK, aE, 1, V, pbA0, pbA1, oA0, oA1, oLA);
            ATTN_STEP(qfB, aK, aE, 0, V, pbB0, pbB1, oB0, oB1, oLB);
            kpa += 128 * Dd; epa += 128 * Dd;
            if (jj < 7) LOADKE(aK, aE, kpa, epa);
        }
        {   // half-iter B: j0 = jj*128 + 64
            bf16x8 V[4];
            V[0] = ldg_frag(vpb0);      V[1] = ldg_frag(vpb1);
            V[2] = ldg_frag(vpb0 + 32); V[3] = ldg_frag(vpb1 + 32);
            vpb0 += 128; vpb1 += 128;
            ATTN_STEP(qfA, bK, bE, 1, V, pbA0, pbA1, oA0, oA1, oLA);
            ATTN_STEP(qfB, bK, bE, 0, V, pbB0, pbB1, oB0, oB1, oLB);
            kpb += 128 * Dd; epb += 128 * Dd;
            if (jj < 7) LOADKE(bK, bE, kpb, epb);
        }
    }

    // normalize and store (oL lanes already hold per-row sums)
    #pragma unroll
    for (int r = 0; r < 4; ++r) {
        const float ia = 1.0f / oLA[r];
        const float ib2 = 1.0f / oLB[r];
        const int srowA = i0 + quad * 4 + r;
        float* opA = out + ((size_t)b * Ss + srowA) * Ee + h * Dd;
        opA[li]      = oA0[r] * ia;
        opA[16 + li] = oA1[r] * ia;
        float* opB = opA + 16 * Ee;          // srowA + 16
        opB[li]      = oB0[r] * ib2;
        opB[16 + li] = oB1[r] * ib2;
    }
}

extern "C" void kernel_launch(void* const* d_in, const int* in_sizes, int n_in,
                              void* d_out, int out_size, void* d_ws, size_t ws_size,
                              hipStream_t stream) {
    const float* x  = (const float*)d_in[0];
    const float* Wq = (const float*)d_in[1];
    const float* Wk = (const float*)d_in[2];
    const float* Wv = (const float*)d_in[3];
    const float* Er = (const float*)d_in[4];
    float* out = (float*)d_out;

    // ws layout (bf16 elements; all offsets 16B-aligned)
    __hip_bfloat16* erb = reinterpret_cast<__hip_bfloat16*>(d_ws);  // [2048][32]
    __hip_bfloat16* Qs  = erb + 65536;
    __hip_bfloat16* Kh  = Qs  + (size_t)Bb * Hh * Ss * Dd;
    __hip_bfloat16* Vt  = Kh  + (size_t)Bb * Hh * Ss * Dd;

    er_convert_kernel<<<64, 256, 0, stream>>>(Er, erb);
    proj_kernel<<<dim3(6, 128), 256, 0, stream>>>(
        x, Wq, Wk, Wv, Qs, Kh, reinterpret_cast<unsigned*>(Vt));
    attn_kernel<<<dim3(1024), 256, 0, stream>>>(Qs, Kh, Vt, erb, out);
}

// Round 8
// 195.278 us; speedup vs baseline: 1.1797x; 1.1797x over previous
//
#include <hip/hip_runtime.h>
#include <hip/hip_bf16.h>

// LocalAttn: B=8 S=1024 E=512 H=16 D=32, rel-pos bias, NO causal mask.
// f32 inputs / f32 output. Internals bf16 for MFMA.
// R8: proj rebuilt -- R7 showed proj itself is ~95us (HBM-latency-bound,
// 60MB fetch from cross-XCD x re-reads + shallow load pipeline). Now:
// bf16 pre-convert, 1D grid id=bx*128+by so id%8==by%8 (all 6 col-blocks
// of the same x rows on ONE XCD -> x L2-resident), register ping-pong
// K-prefetch. Attn reverted to the proven R6 version (81.7us).

typedef short bf16x8 __attribute__((ext_vector_type(8)));   // 8 bf16 (4 VGPRs)
typedef float f32x4 __attribute__((ext_vector_type(4)));
typedef unsigned short u16x4 __attribute__((ext_vector_type(4)));
typedef unsigned int u32x4 __attribute__((ext_vector_type(4)));

#if __has_builtin(__builtin_amdgcn_exp2f)
#define EXP2F(x) __builtin_amdgcn_exp2f(x)
#else
#define EXP2F(x) exp2f(x)
#endif

constexpr int Bb = 8, Ss = 1024, Ee = 512, Hh = 16, Dd = 32;
// log2(e)/sqrt(32): folds the 1/sqrt(D) softmax scale and exp->exp2 into Q.
#define QSCALE 0.25503486f

__device__ __forceinline__ bf16x8 ldg_frag(const __hip_bfloat16* p) {
    return *reinterpret_cast<const bf16x8*>(p);
}

__device__ __forceinline__ unsigned short bf16_bits(float v) {
    return __builtin_bit_cast(unsigned short, __float2bfloat16(v));
}

__device__ __forceinline__ unsigned pack_bf16(float lo, float hi) {
    return (unsigned)bf16_bits(lo) | ((unsigned)bf16_bits(hi) << 16);
}

__device__ __forceinline__ float bperm_f(int addr, float v) {
    return __builtin_bit_cast(float,
        __builtin_amdgcn_ds_bpermute(addr, __builtin_bit_cast(int, v)));
}

// ---------------- f32 -> bf16 conversion into workspace -------------------
// x (1048576 float4-groups), Wq/Wk/Wv (65536 each -> wb rows 0/512/1024),
// Er (16376 groups + 8 zero groups = zero pad row 2047). 4928*256 threads.
__global__ __launch_bounds__(256) void convert_kernel(
    const float* __restrict__ x,  const float* __restrict__ wq,
    const float* __restrict__ wk, const float* __restrict__ wv,
    const float* __restrict__ er,
    __hip_bfloat16* __restrict__ xb, __hip_bfloat16* __restrict__ wb,
    __hip_bfloat16* __restrict__ erb)
{
    const int GX = 1048576, GW = 65536, GE = 16384;  // in float4 groups
    int g = blockIdx.x * 256 + threadIdx.x;          // grid 4928 -> exact
    const float* src;
    __hip_bfloat16* dst;
    int rel;
    if (g < GX)               { src = x;  dst = xb;          rel = g; }
    else if (g < GX +   GW)   { src = wq; dst = wb;          rel = g - GX; }
    else if (g < GX + 2*GW)   { src = wk; dst = wb + 262144; rel = g - GX - GW; }
    else if (g < GX + 3*GW)   { src = wv; dst = wb + 524288; rel = g - GX - 2*GW; }
    else                      { src = er; dst = erb;         rel = g - GX - 3*GW; }
    u16x4 pk = {0, 0, 0, 0};
    if (src != er || rel < 16376) {      // last 8 Er groups: zero pad row
        const float4 v = *reinterpret_cast<const float4*>(src + (size_t)rel * 4);
        pk[0] = bf16_bits(v.x);
        pk[1] = bf16_bits(v.y);
        pk[2] = bf16_bits(v.z);
        pk[3] = bf16_bits(v.w);
    }
    *reinterpret_cast<u16x4*>(dst + (size_t)rel * 4) = pk;
}

// ---------------- projection: Q/K/V = x @ W^T ------------------------------
// 1D grid 768: by = id & 127 (64-row x block), bx = id >> 7 (0..5, 256
// cols of [Q|K|V]). id % 8 == by % 8 -> all col-blocks of one by on the
// same XCD; per-XCD x slice 1 MB + W 1.5 MB fit the 4 MB L2.
// K-loop: register ping-pong, 8 loads hoisted ahead of each 16-MFMA burst.
#define PROJ_LOAD(A, B, OFF) do {                                     \
    _Pragma("unroll")                                                 \
    for (int rf = 0; rf < 4; ++rf) A[rf] = ldg_frag(xp + rf * 16 * Ee + (OFF)); \
    _Pragma("unroll")                                                 \
    for (int t = 0; t < 4; ++t)    B[t] = ldg_frag(wp + t * 16 * Ee + (OFF)); \
} while (0)

#define PROJ_MFMA(A, B) do {                                          \
    _Pragma("unroll")                                                 \
    for (int rf = 0; rf < 4; ++rf)                                    \
        _Pragma("unroll")                                             \
        for (int t = 0; t < 4; ++t)                                   \
            acc[rf][t] = __builtin_amdgcn_mfma_f32_16x16x32_bf16(     \
                A[rf], B[t], acc[rf][t], 0, 0, 0);                    \
} while (0)

__global__ __launch_bounds__(256) void proj_kernel(
    const __hip_bfloat16* __restrict__ xb,   // [8192][512]
    const __hip_bfloat16* __restrict__ wb,   // [1536][512]
    __hip_bfloat16* __restrict__ Qs,   // [B][H][S][D], scaled by QSCALE
    __hip_bfloat16* __restrict__ Kh,   // [B][H][S][D]
    unsigned* __restrict__ Vt32)       // [B][H][D][512 u32] interleaved
{
    const int tid  = threadIdx.x;
    const int wave = tid >> 6;
    const int lane = tid & 63;
    const int li   = lane & 15;
    const int quad = lane >> 4;

    const int by = blockIdx.x & 127;
    const int bx = blockIdx.x >> 7;          // 0..5
    const int m0    = by * 64;
    const int nbase = bx * 256 + wave * 64;
    const int mat   = nbase >> 9;            // 0=Q 1=K 2=V (uniform per wave)
    const int nn0   = nbase & 511;

    f32x4 acc[4][4];
    #pragma unroll
    for (int rf = 0; rf < 4; ++rf)
        #pragma unroll
        for (int t = 0; t < 4; ++t) acc[rf][t] = f32x4{0.f, 0.f, 0.f, 0.f};

    const __hip_bfloat16* xp = xb + (size_t)(m0 + li) * Ee + quad * 8;
    const __hip_bfloat16* wp = wb + (size_t)(nbase + li) * Ee + quad * 8;

    bf16x8 aC[4], bC[4], aN[4], bN[4];
    PROJ_LOAD(aC, bC, 0);
    #pragma unroll
    for (int kk = 0; kk < 8; ++kk) {
        PROJ_LOAD(aN, bN, kk * 64 + 32);
        PROJ_MFMA(aC, bC);
        if (kk < 7) PROJ_LOAD(aC, bC, kk * 64 + 64);
        PROJ_MFMA(aN, bN);
    }

    // epilogue. C layout: col = li, row = quad*4 + reg.
    const int bb = m0 >> 10;           // 64-row block never straddles b
    const int sb = m0 & 1023;
    if (mat == 2) {
        #pragma unroll
        for (int t = 0; t < 4; ++t) {
            int nn = nn0 + t * 16 + li;
            int h = nn >> 5, d = nn & 31;
            size_t base = ((size_t)(bb * Hh + h) * Dd + d) * 512
                        + (sb >> 5) * 16 + quad * 4;
            #pragma unroll
            for (int p = 0; p < 2; ++p) {      // rf pair (2p, 2p+1)
                u32x4 pk;
                #pragma unroll
                for (int r = 0; r < 4; ++r)
                    pk[r] = pack_bf16(acc[2*p][t][r], acc[2*p+1][t][r]);
                *reinterpret_cast<u32x4*>(Vt32 + base + (size_t)p * 16) = pk;
            }
        }
    } else {
        __hip_bfloat16* dst = (mat == 0) ? Qs : Kh;
        const float sc = (mat == 0) ? QSCALE : 1.0f;
        #pragma unroll
        for (int rf = 0; rf < 4; ++rf) {
            const int srow = sb + rf * 16 + quad * 4;
            #pragma unroll
            for (int t = 0; t < 4; ++t) {
                int nn = nn0 + t * 16 + li;
                int h = nn >> 5, d = nn & 31;
                #pragma unroll
                for (int r = 0; r < 4; ++r)
                    dst[((size_t)(bb * Hh + h) * Ss + (srow + r)) * Dd + d] =
                        __float2bfloat16(acc[rf][t][r] * sc);
            }
        }
    }
}

// ---------------- attention (R6 version, 81.7us) ---------------------------
// grid 1024; (b,h) = blockIdx&127 (XCD-local), ib = blockIdx>>7.
// Wave owns TWO 16-row Q strips (32 rows); j-loop steps 64.
// Srel: band MFMA C-frags rotated intra-quad via ds_bpermute.
__global__ __launch_bounds__(256) void attn_kernel(
    const __hip_bfloat16* __restrict__ Qs,
    const __hip_bfloat16* __restrict__ Kh,
    const __hip_bfloat16* __restrict__ Vt,   // bf16 view of Vti (same bytes)
    const __hip_bfloat16* __restrict__ Er,   // [2048][32] bf16, row 2047 = 0
    float* __restrict__ out)                 // [B][S][E] f32
{
    const int tid  = threadIdx.x;
    const int wave = tid >> 6;
    const int lane = tid & 63;
    const int li   = lane & 15;
    const int quad = lane >> 4;

    const int c  = blockIdx.x & 127;
    const int b  = c >> 4;
    const int h  = c & 15;
    const int ib = blockIdx.x >> 7;          // 0..7
    const int i0 = ib * 128 + wave * 32;     // strip A rows i0.., B rows i0+16..

    const __hip_bfloat16* Qp = Qs + (size_t)(b * Hh + h) * Ss * Dd;
    const __hip_bfloat16* Kp = Kh + (size_t)(b * Hh + h) * Ss * Dd;
    const __hip_bfloat16* Vp = Vt + (size_t)(b * Hh + h) * Dd * Ss;

    __shared__ unsigned pb_lds[4][4][16 * 20];   // 20480 B total
    unsigned* pbA0 = pb_lds[wave][0];
    unsigned* pbA1 = pb_lds[wave][1];
    unsigned* pbB0 = pb_lds[wave][2];
    unsigned* pbB1 = pb_lds[wave][3];

    const bf16x8 qfA = ldg_frag(Qp + (i0      + li) * Dd + quad * 8);
    const bf16x8 qfB = ldg_frag(Qp + (i0 + 16 + li) * Dd + quad * 8);

    int addr4[4];
    bool cond[4];
    #pragma unroll
    for (int r = 0; r < 4; ++r) {
        const int row = quad * 4 + r;
        addr4[r] = (16 * quad + ((li - row + 15) & 15)) * 4;
        cond[r]  = (li <= row);            // bc < 16 -> lower band block
    }
    const int pbw = quad * 80 + li;        // pb write base (u32)
    const int pbr = li * 20 + quad * 4;    // pb read base (16B aligned)

    f32x4 oA0 = f32x4{0,0,0,0}, oA1 = f32x4{0,0,0,0};
    f32x4 oB0 = f32x4{0,0,0,0}, oB1 = f32x4{0,0,0,0};
    float lsumA[4] = {0,0,0,0}, lsumB[4] = {0,0,0,0};
    const f32x4 zero = f32x4{0,0,0,0};

    for (int j0 = 0; j0 < Ss; j0 += 64) {
        bf16x8 k0 = ldg_frag(Kp + (j0      + li) * Dd + quad * 8);
        bf16x8 k1 = ldg_frag(Kp + (j0 + 16 + li) * Dd + quad * 8);
        bf16x8 k2 = ldg_frag(Kp + (j0 + 32 + li) * Dd + quad * 8);
        bf16x8 k3 = ldg_frag(Kp + (j0 + 48 + li) * Dd + quad * 8);
        const int rb = j0 - i0 + 1008;       // strip A base; rb-16 >= 0
        bf16x8 em = ldg_frag(Er + (rb - 16 + li) * Dd + quad * 8);
        bf16x8 e0 = ldg_frag(Er + (rb      + li) * Dd + quad * 8);
        bf16x8 e1 = ldg_frag(Er + (rb + 16 + li) * Dd + quad * 8);
        bf16x8 e2 = ldg_frag(Er + (rb + 32 + li) * Dd + quad * 8);
        bf16x8 e3 = ldg_frag(Er + (rb + 48 + li) * Dd + quad * 8);
        bf16x8 e4 = ldg_frag(Er + (rb + 64 + li) * Dd + quad * 8);
        bf16x8 v0 = ldg_frag(Vp + (li     ) * Ss + j0 + quad * 8);
        bf16x8 v1 = ldg_frag(Vp + (li + 16) * Ss + j0 + quad * 8);
        bf16x8 v2 = ldg_frag(Vp + (li     ) * Ss + j0 + 32 + quad * 8);
        bf16x8 v3 = ldg_frag(Vp + (li + 16) * Ss + j0 + 32 + quad * 8);

        // ================= strip A (rows i0..i0+15) =================
        {
            f32x4 s0 = __builtin_amdgcn_mfma_f32_16x16x32_bf16(qfA, k0, zero, 0, 0, 0);
            f32x4 s1 = __builtin_amdgcn_mfma_f32_16x16x32_bf16(qfA, k1, zero, 0, 0, 0);
            f32x4 s2 = __builtin_amdgcn_mfma_f32_16x16x32_bf16(qfA, k2, zero, 0, 0, 0);
            f32x4 s3 = __builtin_amdgcn_mfma_f32_16x16x32_bf16(qfA, k3, zero, 0, 0, 0);
            f32x4 q0 = __builtin_amdgcn_mfma_f32_16x16x32_bf16(qfA, e0, zero, 0, 0, 0);
            f32x4 q1 = __builtin_amdgcn_mfma_f32_16x16x32_bf16(qfA, e1, zero, 0, 0, 0);
            f32x4 q2 = __builtin_amdgcn_mfma_f32_16x16x32_bf16(qfA, e2, zero, 0, 0, 0);
            f32x4 q3 = __builtin_amdgcn_mfma_f32_16x16x32_bf16(qfA, e3, zero, 0, 0, 0);
            f32x4 q4 = __builtin_amdgcn_mfma_f32_16x16x32_bf16(qfA, e4, zero, 0, 0, 0);
            float p0[4], p1[4], p2[4], p3[4];
            #pragma unroll
            for (int r = 0; r < 4; ++r) {
                float f0 = bperm_f(addr4[r], q0[r]);
                float f1 = bperm_f(addr4[r], q1[r]);
                float f2 = bperm_f(addr4[r], q2[r]);
                float f3 = bperm_f(addr4[r], q3[r]);
                float f4 = bperm_f(addr4[r], q4[r]);
                p0[r] = EXP2F(s0[r] + (cond[r] ? f0 : f1));
                p1[r] = EXP2F(s1[r] + (cond[r] ? f1 : f2));
                p2[r] = EXP2F(s2[r] + (cond[r] ? f2 : f3));
                p3[r] = EXP2F(s3[r] + (cond[r] ? f3 : f4));
                lsumA[r] += (p0[r] + p1[r]) + (p2[r] + p3[r]);
            }
            #pragma unroll
            for (int r = 0; r < 4; ++r) {
                pbA0[pbw + 20 * r] = pack_bf16(p0[r], p1[r]);
                pbA1[pbw + 20 * r] = pack_bf16(p2[r], p3[r]);
            }
            bf16x8 pf0 = *reinterpret_cast<const bf16x8*>(&pbA0[pbr]);
            bf16x8 pf1 = *reinterpret_cast<const bf16x8*>(&pbA1[pbr]);
            oA0 = __builtin_amdgcn_mfma_f32_16x16x32_bf16(pf0, v0, oA0, 0, 0, 0);
            oA1 = __builtin_amdgcn_mfma_f32_16x16x32_bf16(pf0, v1, oA1, 0, 0, 0);
            oA0 = __builtin_amdgcn_mfma_f32_16x16x32_bf16(pf1, v2, oA0, 0, 0, 0);
            oA1 = __builtin_amdgcn_mfma_f32_16x16x32_bf16(pf1, v3, oA1, 0, 0, 0);
        }

        // ================= strip B (rows i0+16..i0+31) ==============
        {
            f32x4 s0 = __builtin_amdgcn_mfma_f32_16x16x32_bf16(qfB, k0, zero, 0, 0, 0);
            f32x4 s1 = __builtin_amdgcn_mfma_f32_16x16x32_bf16(qfB, k1, zero, 0, 0, 0);
            f32x4 s2 = __builtin_amdgcn_mfma_f32_16x16x32_bf16(qfB, k2, zero, 0, 0, 0);
            f32x4 s3 = __builtin_amdgcn_mfma_f32_16x16x32_bf16(qfB, k3, zero, 0, 0, 0);
            f32x4 q0 = __builtin_amdgcn_mfma_f32_16x16x32_bf16(qfB, em, zero, 0, 0, 0);
            f32x4 q1 = __builtin_amdgcn_mfma_f32_16x16x32_bf16(qfB, e0, zero, 0, 0, 0);
            f32x4 q2 = __builtin_amdgcn_mfma_f32_16x16x32_bf16(qfB, e1, zero, 0, 0, 0);
            f32x4 q3 = __builtin_amdgcn_mfma_f32_16x16x32_bf16(qfB, e2, zero, 0, 0, 0);
            f32x4 q4 = __builtin_amdgcn_mfma_f32_16x16x32_bf16(qfB, e3, zero, 0, 0, 0);
            float p0[4], p1[4], p2[4], p3[4];
            #pragma unroll
            for (int r = 0; r < 4; ++r) {
                float f0 = bperm_f(addr4[r], q0[r]);
                float f1 = bperm_f(addr4[r], q1[r]);
                float f2 = bperm_f(addr4[r], q2[r]);
                float f3 = bperm_f(addr4[r], q3[r]);
                float f4 = bperm_f(addr4[r], q4[r]);
                p0[r] = EXP2F(s0[r] + (cond[r] ? f0 : f1));
                p1[r] = EXP2F(s1[r] + (cond[r] ? f1 : f2));
                p2[r] = EXP2F(s2[r] + (cond[r] ? f2 : f3));
                p3[r] = EXP2F(s3[r] + (cond[r] ? f3 : f4));
                lsumB[r] += (p0[r] + p1[r]) + (p2[r] + p3[r]);
            }
            #pragma unroll
            for (int r = 0; r < 4; ++r) {
                pbB0[pbw + 20 * r] = pack_bf16(p0[r], p1[r]);
                pbB1[pbw + 20 * r] = pack_bf16(p2[r], p3[r]);
            }
            bf16x8 pf0 = *reinterpret_cast<const bf16x8*>(&pbB0[pbr]);
            bf16x8 pf1 = *reinterpret_cast<const bf16x8*>(&pbB1[pbr]);
            oB0 = __builtin_amdgcn_mfma_f32_16x16x32_bf16(pf0, v0, oB0, 0, 0, 0);
            oB1 = __builtin_amdgcn_mfma_f32_16x16x32_bf16(pf0, v1, oB1, 0, 0, 0);
            oB0 = __builtin_amdgcn_mfma_f32_16x16x32_bf16(pf1, v2, oB0, 0, 0, 0);
            oB1 = __builtin_amdgcn_mfma_f32_16x16x32_bf16(pf1, v3, oB1, 0, 0, 0);
        }
    }

    #pragma unroll
    for (int r = 0; r < 4; ++r) {
        float va = lsumA[r], vb = lsumB[r];
        va += __shfl_xor(va, 1, 64);  vb += __shfl_xor(vb, 1, 64);
        va += __shfl_xor(va, 2, 64);  vb += __shfl_xor(vb, 2, 64);
        va += __shfl_xor(va, 4, 64);  vb += __shfl_xor(vb, 4, 64);
        va += __shfl_xor(va, 8, 64);  vb += __shfl_xor(vb, 8, 64);
        lsumA[r] = 1.0f / va;
        lsumB[r] = 1.0f / vb;
    }
    #pragma unroll
    for (int r = 0; r < 4; ++r) {
        const int srowA = i0 + quad * 4 + r;
        float* opA = out + ((size_t)b * Ss + srowA) * Ee + h * Dd;
        opA[li]      = oA0[r] * lsumA[r];
        opA[16 + li] = oA1[r] * lsumA[r];
        float* opB = opA + 16 * Ee;          // srowA + 16
        opB[li]      = oB0[r] * lsumB[r];
        opB[16 + li] = oB1[r] * lsumB[r];
    }
}

extern "C" void kernel_launch(void* const* d_in, const int* in_sizes, int n_in,
                              void* d_out, int out_size, void* d_ws, size_t ws_size,
                              hipStream_t stream) {
    const float* x  = (const float*)d_in[0];
    const float* Wq = (const float*)d_in[1];
    const float* Wk = (const float*)d_in[2];
    const float* Wv = (const float*)d_in[3];
    const float* Er = (const float*)d_in[4];
    float* out = (float*)d_out;

    // ws layout (bf16 elements; all offsets 16B-aligned)
    __hip_bfloat16* xb  = reinterpret_cast<__hip_bfloat16*>(d_ws);
    __hip_bfloat16* wbb = xb  + (size_t)8192 * 512;
    __hip_bfloat16* erb = wbb + (size_t)1536 * 512;     // [2048][32]
    __hip_bfloat16* Qs  = erb + 65536;
    __hip_bfloat16* Kh  = Qs  + (size_t)Bb * Hh * Ss * Dd;
    __hip_bfloat16* Vt  = Kh  + (size_t)Bb * Hh * Ss * Dd;

    convert_kernel<<<4928, 256, 0, stream>>>(x, Wq, Wk, Wv, Er, xb, wbb, erb);
    proj_kernel<<<dim3(768), 256, 0, stream>>>(
        xb, wbb, Qs, Kh, reinterpret_cast<unsigned*>(Vt));
    attn_kernel<<<dim3(1024), 256, 0, stream>>>(Qs, Kh, Vt, erb, out);
}